// Round 20
// baseline (93.266 us; speedup 1.0000x reference)
//
#include <hip/hip_runtime.h>
#include <hip/hip_bf16.h>

#define B_  2
#define T_  2048
#define D_  512
#define DM_ 64
#define H_  16
#define NQ_ (DM_*H_)   // 1024
#define NT_ (T_/64)    // 32 key tiles

typedef __bf16 bf16x8 __attribute__((ext_vector_type(8)));
typedef __bf16 bf16x4 __attribute__((ext_vector_type(4)));
typedef float  f32x4  __attribute__((ext_vector_type(4)));
typedef unsigned int u32;

static __device__ __forceinline__ __bf16 bfc(float x) { return (__bf16)x; }
static __device__ __forceinline__ unsigned short f2bf(float x) {
    __bf16 b = (__bf16)x;
    unsigned short u;
    __builtin_memcpy(&u, &b, 2);
    return u;
}
static __device__ __forceinline__ u32 pack2bf(float a, float b) {
    return (u32)f2bf(a) | ((u32)f2bf(b) << 16);
}

#if __has_builtin(__builtin_amdgcn_exp2f)
static __device__ __forceinline__ float EXP2(float x) { return __builtin_amdgcn_exp2f(x); }
#else
static __device__ __forceinline__ float EXP2(float x) {
    float r; asm("v_exp_f32 %0, %1\ns_nop 0" : "=v"(r) : "v"(x)); return r;
}
#endif

// async global->LDS, 16B per lane; dest = wave-uniform base + lane*16
#define GLOAD16(gp, lp) \
    __builtin_amdgcn_global_load_lds((const __attribute__((address_space(1))) u32*)(gp), \
                                     (__attribute__((address_space(3))) u32*)(lp), 16, 0, 0)

// ---------------------------------------------------------------------------
// fused prep: [0,1024) pad | [1024,2048) data cvt | [2048,3584) qkv wtrans |
// [3584,4096) wo wtrans.  QKV wtrans writes permuted rows n' = h*64+dm.
// ---------------------------------------------------------------------------
__global__ __launch_bounds__(256)
void prep_kernel(const float* __restrict__ mask, float* __restrict__ padb,
                 const float* __restrict__ data, unsigned short* __restrict__ dataB,
                 const float* __restrict__ wq, const float* __restrict__ wk,
                 const float* __restrict__ wv, unsigned short* __restrict__ btall,
                 const float* __restrict__ wo, unsigned short* __restrict__ wot)
{
    __shared__ float t[32][33];
    const int bid = blockIdx.x;
    const int tid = threadIdx.x;
    if (bid < 1024) {
        const int row  = bid * 4 + (tid >> 6);
        const int lane = tid & 63;
        const float* p = mask + (size_t)row * D_;
        float4 a = *(const float4*)&p[lane * 8];
        float4 b = *(const float4*)&p[lane * 8 + 4];
        float s = a.x + a.y + a.z + a.w + b.x + b.y + b.z + b.w;
#pragma unroll
        for (int off = 32; off; off >>= 1) s += __shfl_down(s, off);
        if (lane == 0) padb[row] = (s == 0.0f) ? -1e9f : 0.0f;
    } else if (bid < 2048) {
        int i = ((bid - 1024) * 256 + tid) * 8;
        float4 a = *(const float4*)&data[i];
        float4 b = *(const float4*)&data[i + 4];
        bf16x8 u = {bfc(a.x), bfc(a.y), bfc(a.z), bfc(a.w),
                    bfc(b.x), bfc(b.y), bfc(b.z), bfc(b.w)};
        *(bf16x8*)&dataB[i] = u;
    } else if (bid < 3584) {
        const int idx = bid - 2048;
        const int z = idx >> 9, rem = idx & 511;
        const int c0 = (rem & 31) * 32, r0 = (rem >> 5) * 32;   // C=1024, R=512
        const float* in = (z == 0) ? wq : (z == 1) ? wk : wv;
        unsigned short* out = btall + (size_t)z * NQ_ * D_;
        const int tx = tid & 31, ty = tid >> 5;
#pragma unroll
        for (int i = 0; i < 4; ++i)
            t[ty * 4 + i][tx] = in[(size_t)(r0 + ty * 4 + i) * NQ_ + c0 + tx];
        __syncthreads();
#pragma unroll
        for (int i = 0; i < 4; ++i) {
            int c  = c0 + ty * 4 + i;
            int rp = (c & 15) * 64 + (c >> 4);   // n' = h*64 + dm
            out[(size_t)rp * D_ + r0 + tx] = f2bf(t[tx][ty * 4 + i]);
        }
    } else {
        const int idx = bid - 3584;
        const int c0 = (idx & 15) * 32, r0 = (idx >> 4) * 32;   // C=512, R=1024
        const int tx = tid & 31, ty = tid >> 5;
#pragma unroll
        for (int i = 0; i < 4; ++i)
            t[ty * 4 + i][tx] = wo[(size_t)(r0 + ty * 4 + i) * D_ + c0 + tx];
        __syncthreads();
#pragma unroll
        for (int i = 0; i < 4; ++i)
            wot[(size_t)(c0 + ty * 4 + i) * NQ_ + r0 + tx] = f2bf(t[tx][ty * 4 + i]);
    }
}

// ---------------------------------------------------------------------------
// fused QKV GEMM, 64x128 tile, XCD-CHUNKED 1-D GRID (1536 blocks): each XCD
// owns 8 contiguous m-panels x all 24 n-tiles -> A-chunk (512KB) + BtAll
// (3MB) are L2-resident per XCD; fetch ~28MB instead of ~70MB.
// ---------------------------------------------------------------------------
__global__ __launch_bounds__(256)
void mgemm_qkv_kernel(const unsigned short* __restrict__ A,
                      const unsigned short* __restrict__ BtAll,
                      const float* __restrict__ bq, const float* __restrict__ bk,
                      const float* __restrict__ bv,
                      unsigned short* __restrict__ Qh, unsigned short* __restrict__ Kh,
                      unsigned short* __restrict__ Vt, float alpha_q)
{
    const int K = D_;
    __shared__ __align__(16) unsigned short Al[2][64 * 64];    // 16KB
    __shared__ __align__(16) unsigned short Bl[2][128 * 64];   // 32KB

    const int tid = threadIdx.x;
    const int w  = tid >> 6, l = tid & 63;
    const int lo = l & 15,  g = l >> 4;
    const int wri = w >> 1, wci = w & 1;

    // XCD-chunked decode: f&7 = XCD; per XCD: 8 m-panels x 24 n-tiles.
    const int f  = blockIdx.x;
    const int s  = f >> 3;                 // 0..191
    const int mt = (f & 7) * 8 + (s / 24); // 0..63
    const int nt = s % 24;                 // 0..23
    const int m0 = mt * 64, n0 = nt * 128;

    const int lrow = l >> 3;
    const int lslot = (l & 7) ^ lrow;      // pre-swizzled source slot

    f32x4 acc[2][4] = {};
    const int nk = K >> 6;   // 8

#pragma unroll
    for (int p = 0; p < 2; ++p) {
        int br = w * 16 + p * 8;
        GLOAD16(A + (size_t)(m0 + br + lrow) * K + lslot * 8, (char*)Al[0] + br * 128);
    }
#pragma unroll
    for (int p = 0; p < 4; ++p) {
        int br = w * 32 + p * 8;
        GLOAD16(BtAll + (size_t)(n0 + br + lrow) * K + lslot * 8, (char*)Bl[0] + br * 128);
    }
    __syncthreads();

    for (int t = 0; t < nk; ++t) {
        const int cur = t & 1;
        if (t + 1 < nk) {
            const int k0 = (t + 1) << 6;
#pragma unroll
            for (int p = 0; p < 2; ++p) {
                int br = w * 16 + p * 8;
                GLOAD16(A + (size_t)(m0 + br + lrow) * K + k0 + lslot * 8,
                        (char*)Al[cur ^ 1] + br * 128);
            }
#pragma unroll
            for (int p = 0; p < 4; ++p) {
                int br = w * 32 + p * 8;
                GLOAD16(BtAll + (size_t)(n0 + br + lrow) * K + k0 + lslot * 8,
                        (char*)Bl[cur ^ 1] + br * 128);
            }
        }
#pragma unroll
        for (int kk = 0; kk < 2; ++kk) {
            bf16x8 af[2], bfr[4];
#pragma unroll
            for (int i = 0; i < 2; ++i) {
                int row = wri * 32 + i * 16 + lo;
                af[i] = *(const bf16x8*)&Al[cur][row * 64 + ((((kk << 2) + g) ^ (row & 7)) << 3)];
            }
#pragma unroll
            for (int j = 0; j < 4; ++j) {
                int col = wci * 64 + j * 16 + lo;
                bfr[j] = *(const bf16x8*)&Bl[cur][col * 64 + ((((kk << 2) + g) ^ (col & 7)) << 3)];
            }
#pragma unroll
            for (int i = 0; i < 2; ++i)
#pragma unroll
                for (int j = 0; j < 4; ++j)
                    acc[i][j] = __builtin_amdgcn_mfma_f32_16x16x32_bf16(af[i], bfr[j], acc[i][j], 0, 0, 0);
        }
        __syncthreads();
    }

    const int seg = n0 >> 10;                  // 0:Q 1:K 2:V
    const int n0l = n0 & 1023;
    const float* bias = (seg == 0) ? bq : (seg == 1) ? bk : bv;
    const float alpha = (seg == 0) ? alpha_q : 1.0f;
    const int h = (n0l >> 6) + wci;            // this wave's head

    float bb[4];
#pragma unroll
    for (int j = 0; j < 4; ++j) bb[j] = bias[(j * 16 + lo) * 16 + h];

    if (seg < 2) {
        unsigned short* o16 = (seg == 0) ? Qh : Kh;
        unsigned short* hb = (unsigned short*)Al + wci * (64 * 64);  // 8KB/head
#pragma unroll
        for (int i = 0; i < 2; ++i)
#pragma unroll
            for (int jj = 0; jj < 4; ++jj) {
                int ml = wri * 32 + i * 16 + g * 4 + jj;
#pragma unroll
                for (int j = 0; j < 4; ++j) {
                    int dm = j * 16 + lo;
                    int off = ml * 64 + (((dm >> 3) ^ (ml & 7)) << 3) + (dm & 7);
                    hb[off] = f2bf((acc[i][j][jj] + bb[j]) * alpha);
                }
            }
        const int rrow = l >> 3, rch = l & 7;
#pragma unroll
        for (int p = 0; p < 4; ++p) {
            int ml = wri * 32 + p * 8 + rrow;
            bf16x8 v = *(const bf16x8*)&hb[ml * 64 + ((rch ^ (ml & 7)) << 3)];
            int m = m0 + ml;
            int t = m & (T_ - 1), bidx = m >> 11;
            *(bf16x8*)&o16[(((size_t)(bidx * H_ + h)) * T_ + t) * DM_ + rch * 8] = v;
        }
    } else {
#pragma unroll
        for (int i = 0; i < 2; ++i)
#pragma unroll
            for (int j = 0; j < 4; ++j) {
                int m = m0 + wri * 32 + i * 16 + g * 4;
                int t = m & (T_ - 1), bidx = m >> 11;
                int dm = j * 16 + lo;
                bf16x4 u = {bfc(acc[i][j][0] + bb[j]), bfc(acc[i][j][1] + bb[j]),
                            bfc(acc[i][j][2] + bb[j]), bfc(acc[i][j][3] + bb[j])};
                *(bf16x4*)&Vt[((size_t)(bidx * H_ + h) * DM_ + dm) * T_ + t] = u;
            }
    }
}

// ---------------------------------------------------------------------------
// out-projection GEMM (fp32 out), 64x64 tile, XCD-chunked 1-D grid (512
// blocks): each XCD owns 8 m-panels x 8 n-tiles; wot (1MB) L2-resident.
// ---------------------------------------------------------------------------
__global__ __launch_bounds__(256)
void mgemm_out_kernel(const unsigned short* __restrict__ A,
                      const unsigned short* __restrict__ Bt,
                      const float* __restrict__ bias, float* __restrict__ out,
                      int M, int N, int K)
{
    __shared__ __align__(16) unsigned short Al[2][64 * 64];
    __shared__ __align__(16) unsigned short Bl[2][64 * 64];

    const int tid = threadIdx.x;
    const int w  = tid >> 6, l = tid & 63;
    const int lo = l & 15,  g = l >> 4;
    const int wri = w >> 1, wci = w & 1;

    const int f  = blockIdx.x;
    const int s  = f >> 3;                 // 0..63
    const int mt = (f & 7) * 8 + (s >> 3); // 0..63
    const int nt = s & 7;                  // 0..7
    const int m0 = mt * 64, n0 = nt * 64;

    const int lrow = l >> 3;
    const int lslot = (l & 7) ^ lrow;

    f32x4 acc[2][2] = {};
    const int nk = K >> 6;   // 16

#pragma unroll
    for (int p = 0; p < 2; ++p) {
        int br = w * 16 + p * 8;
        GLOAD16(A  + (size_t)(m0 + br + lrow) * K + lslot * 8, (char*)Al[0] + br * 128);
        GLOAD16(Bt + (size_t)(n0 + br + lrow) * K + lslot * 8, (char*)Bl[0] + br * 128);
    }
    __syncthreads();

    for (int t = 0; t < nk; ++t) {
        const int cur = t & 1;
        if (t + 1 < nk) {
            const int k0 = (t + 1) << 6;
#pragma unroll
            for (int p = 0; p < 2; ++p) {
                int br = w * 16 + p * 8;
                GLOAD16(A  + (size_t)(m0 + br + lrow) * K + k0 + lslot * 8,
                        (char*)Al[cur ^ 1] + br * 128);
                GLOAD16(Bt + (size_t)(n0 + br + lrow) * K + k0 + lslot * 8,
                        (char*)Bl[cur ^ 1] + br * 128);
            }
        }
#pragma unroll
        for (int kk = 0; kk < 2; ++kk) {
            bf16x8 af[2], bfr[2];
#pragma unroll
            for (int i = 0; i < 2; ++i) {
                int row = wri * 32 + i * 16 + lo;
                af[i] = *(const bf16x8*)&Al[cur][row * 64 + ((((kk << 2) + g) ^ (row & 7)) << 3)];
                int col = wci * 32 + i * 16 + lo;
                bfr[i] = *(const bf16x8*)&Bl[cur][col * 64 + ((((kk << 2) + g) ^ (col & 7)) << 3)];
            }
#pragma unroll
            for (int i = 0; i < 2; ++i)
#pragma unroll
                for (int j = 0; j < 2; ++j)
                    acc[i][j] = __builtin_amdgcn_mfma_f32_16x16x32_bf16(af[i], bfr[j], acc[i][j], 0, 0, 0);
        }
        __syncthreads();
    }

    const int mb = m0 + wri * 32 + g * 4;
#pragma unroll
    for (int j = 0; j < 2; ++j) {
        int n = n0 + wci * 32 + j * 16 + lo;
        float bb = bias[n];
#pragma unroll
        for (int i = 0; i < 2; ++i)
#pragma unroll
            for (int jj = 0; jj < 4; ++jj) {
                int m = mb + i * 16 + jj;
                out[(size_t)m * N + n] = acc[i][j][jj] + bb;
            }
    }
}

// ---------------------------------------------------------------------------
// MFMA flash attention v18 (unchanged): triple-buffered K/V, counted vmcnt,
// raw s_barrier, P in registers, no-max softmax, XCD-aware grid.
// ---------------------------------------------------------------------------
__global__ __launch_bounds__(256, 2)
void attn_kernel(const unsigned short* __restrict__ Qh,
                 const unsigned short* __restrict__ Kh,
                 const unsigned short* __restrict__ Vt,
                 const float* __restrict__ padb,
                 unsigned short* __restrict__ ctx)
{
    __shared__ __align__(16) unsigned short Ks[3][64 * 64];   // 24KB
    __shared__ __align__(16) unsigned short Vs[3][64 * 64];   // 24KB
    __shared__ __align__(16) float pbs[T_];                   // 8KB

    const int tid  = threadIdx.x;
    const int w    = tid >> 6;
    const int l    = tid & 63;
    const int lo16 = l & 15;
    const int g    = l >> 4;
    const int lrow = l >> 3;
    const int lslot = (l & 7) ^ lrow;

    const int f   = blockIdx.x;
    const int s   = f >> 3;
    const int bh  = (f & 7) * 4 + (s >> 4);
    const int q0  = (s & 15) * 128;
    const int bb  = bh >> 4;
    const int hh  = bh & 15;

    bf16x8 qf[2][2];
#pragma unroll
    for (int qt = 0; qt < 2; ++qt) {
        const unsigned short* Qp =
            Qh + ((size_t)bh * T_ + q0 + w * 32 + qt * 16 + lo16) * DM_ + g * 8;
        qf[qt][0] = *(const bf16x8*)(Qp);
        qf[qt][1] = *(const bf16x8*)(Qp + 32);
    }

    const unsigned short* kgp =
        Kh + (size_t)bh * T_ * DM_ + (size_t)(w * 16 + lrow) * DM_ + lslot * 8;
    const unsigned short* vgp =
        Vt + (size_t)bh * DM_ * T_ + (size_t)(w * 16 + lrow) * T_ + lslot * 8;

    {
        const float* src = padb + bb * T_ + tid * 8;
        float4 a = *(const float4*)(src);
        float4 b = *(const float4*)(src + 4);
        *(float4*)&pbs[tid * 8]     = a;
        *(float4*)&pbs[tid * 8 + 4] = b;
    }

    GLOAD16(kgp,           (char*)Ks[0] + (w * 16) * 128);
    GLOAD16(kgp + 8 * DM_, (char*)Ks[0] + (w * 16 + 8) * 128);
    GLOAD16(vgp,           (char*)Vs[0] + (w * 16) * 128);
    GLOAD16(vgp + 8 * T_,  (char*)Vs[0] + (w * 16 + 8) * 128);
    kgp += 64 * DM_; vgp += 64;
    GLOAD16(kgp,           (char*)Ks[1] + (w * 16) * 128);
    GLOAD16(kgp + 8 * DM_, (char*)Ks[1] + (w * 16 + 8) * 128);
    GLOAD16(vgp,           (char*)Vs[1] + (w * 16) * 128);
    GLOAD16(vgp + 8 * T_,  (char*)Vs[1] + (w * 16 + 8) * 128);
    kgp += 64 * DM_; vgp += 64;

    asm volatile("s_waitcnt vmcnt(4)" ::: "memory");
    __builtin_amdgcn_sched_barrier(0);
    __builtin_amdgcn_s_barrier();

    f32x4 oa[2][4] = {};
    f32x4 ls4[2] = {};

    char* Kr = (char*)Ks[0]; char* Kn = (char*)Ks[1]; char* Kw = (char*)Ks[2];
    char* Vr = (char*)Vs[0]; char* Vn = (char*)Vs[1]; char* Vw = (char*)Vs[2];

    for (int t = 0; t < NT_; ++t) {
        const bool more2 = (t + 2 < NT_);
        if (more2) {
            GLOAD16(kgp,           Kw + (w * 16) * 128);
            GLOAD16(kgp + 8 * DM_, Kw + (w * 16 + 8) * 128);
            GLOAD16(vgp,           Vw + (w * 16) * 128);
            GLOAD16(vgp + 8 * T_,  Vw + (w * 16 + 8) * 128);
            kgp += 64 * DM_;
            vgp += 64;
        }

        f32x4 sa[2][4];
#pragma unroll
        for (int nt = 0; nt < 4; ++nt) {
            f32x4 pb4 = *(const f32x4*)&pbs[t * 64 + nt * 16 + g * 4];
            sa[0][nt] = pb4;
            sa[1][nt] = pb4;
        }
        __builtin_amdgcn_s_setprio(1);
#pragma unroll
        for (int ks = 0; ks < 2; ++ks) {
#pragma unroll
            for (int nt = 0; nt < 4; ++nt) {
                int row = nt * 16 + lo16;
                int off = (row * 128 + ks * 64 + g * 16) ^ ((row & 7) << 4);
                bf16x8 kf = *(const bf16x8*)(Kr + off);
#pragma unroll
                for (int qt = 0; qt < 2; ++qt)
                    sa[qt][nt] = __builtin_amdgcn_mfma_f32_16x16x32_bf16(kf, qf[qt][ks], sa[qt][nt], 0, 0, 0);
            }
        }
        __builtin_amdgcn_s_setprio(0);

        u32 pw[2][4][2];
#pragma unroll
        for (int qt = 0; qt < 2; ++qt)
#pragma unroll
            for (int nt = 0; nt < 4; ++nt) {
                float e0 = EXP2(sa[qt][nt][0]);
                float e1 = EXP2(sa[qt][nt][1]);
                float e2 = EXP2(sa[qt][nt][2]);
                float e3 = EXP2(sa[qt][nt][3]);
                ls4[qt] += (f32x4){e0, e1, e2, e3};
                pw[qt][nt][0] = pack2bf(e0, e1);
                pw[qt][nt][1] = pack2bf(e2, e3);
            }
        bf16x8 pf[2][2];
#pragma unroll
        for (int qt = 0; qt < 2; ++qt)
#pragma unroll
            for (int ks = 0; ks < 2; ++ks) {
                uint4 uu;
                uu.x = pw[qt][2 * ks][0];
                uu.y = pw[qt][2 * ks][1];
                uu.z = pw[qt][2 * ks + 1][0];
                uu.w = pw[qt][2 * ks + 1][1];
                pf[qt][ks] = *(const bf16x8*)&uu;
            }

        __builtin_amdgcn_s_setprio(1);
#pragma unroll
        for (int ks = 0; ks < 2; ++ks)
#pragma unroll
            for (int nd = 0; nd < 4; ++nd) {
                int row = nd * 16 + lo16;
                int sw = (row & 7) << 4;
                int o0 = (row * 128 + ks * 64 + g * 8) ^ sw;
                int o1 = (row * 128 + ks * 64 + 32 + g * 8) ^ sw;
                uint2 a = *(const uint2*)(Vr + o0);
                uint2 b = *(const uint2*)(Vr + o1);
                uint4 uu; uu.x = a.x; uu.y = a.y; uu.z = b.x; uu.w = b.y;
                bf16x8 vf = *(const bf16x8*)&uu;
#pragma unroll
                for (int qt = 0; qt < 2; ++qt)
                    oa[qt][nd] = __builtin_amdgcn_mfma_f32_16x16x32_bf16(vf, pf[qt][ks], oa[qt][nd], 0, 0, 0);
            }
        __builtin_amdgcn_s_setprio(0);

        if (t + 1 < NT_) {
            if (more2) {
                asm volatile("s_waitcnt vmcnt(4)" ::: "memory");
            } else {
                asm volatile("s_waitcnt vmcnt(0)" ::: "memory");
            }
            __builtin_amdgcn_sched_barrier(0);
            __builtin_amdgcn_s_barrier();
        }

        { char* tk = Kr; Kr = Kn; Kn = Kw; Kw = tk;
          char* tv = Vr; Vr = Vn; Vn = Vw; Vw = tv; }
    }

#pragma unroll
    for (int qt = 0; qt < 2; ++qt) {
        float lt = (ls4[qt][0] + ls4[qt][1]) + (ls4[qt][2] + ls4[qt][3]);
        lt += __shfl_xor(lt, 16);
        lt += __shfl_xor(lt, 32);
        float linv = 1.0f / lt;
        const size_t crow =
            ((size_t)(bb * T_ + q0 + w * 32 + qt * 16 + lo16)) * NQ_ + hh * DM_;
#pragma unroll
        for (int nd = 0; nd < 4; ++nd) {
            bf16x4 u = {bfc(oa[qt][nd][0] * linv), bfc(oa[qt][nd][1] * linv),
                        bfc(oa[qt][nd][2] * linv), bfc(oa[qt][nd][3] * linv)};
            *(bf16x4*)&ctx[crow + nd * 16 + g * 4] = u;
        }
    }
}

// ---------------------------------------------------------------------------
extern "C" void kernel_launch(void* const* d_in, const int* in_sizes, int n_in,
                              void* d_out, int out_size, void* d_ws, size_t ws_size,
                              hipStream_t stream) {
    const float* data = (const float*)d_in[0];
    const float* mask = (const float*)d_in[1];
    const float* wq   = (const float*)d_in[2];
    const float* bq   = (const float*)d_in[3];
    const float* wk   = (const float*)d_in[4];
    const float* bk   = (const float*)d_in[5];
    const float* wv   = (const float*)d_in[6];
    const float* bv   = (const float*)d_in[7];
    const float* wo   = (const float*)d_in[8];
    const float* bo   = (const float*)d_in[9];
    float* out = (float*)d_out;

    char* ws = (char*)d_ws;
    const size_t MB = 1024 * 1024;
    unsigned short* Qh    = (unsigned short*)(ws);             // 8MB
    unsigned short* Kh    = (unsigned short*)(ws +  8 * MB);   // 8MB
    unsigned short* Vt    = (unsigned short*)(ws + 16 * MB);   // 8MB
    unsigned short* CTX   = (unsigned short*)(ws + 24 * MB);   // 8MB (bf16)
    unsigned short* dataB = (unsigned short*)(ws + 32 * MB);   // 4MB
    unsigned short* BtAll = (unsigned short*)(ws + 36 * MB);   // 3MB
    unsigned short* wot   = (unsigned short*)(ws + 39 * MB);   // 1MB
    float*          padb  = (float*)         (ws + 40 * MB);   // 16KB

    const int M = B_ * T_;                 // 4096
    const float alpha_q = 0.125f * 1.44269504089f;

    prep_kernel<<<4096, 256, 0, stream>>>(mask, padb, data, dataB,
                                          wq, wk, wv, BtAll, wo, wot);

    mgemm_qkv_kernel<<<1536, 256, 0, stream>>>(
        dataB, BtAll, bq, bk, bv, Qh, Kh, Vt, alpha_q);

    attn_kernel<<<512, 256, 0, stream>>>(Qh, Kh, Vt, padb, CTX);

    mgemm_out_kernel<<<512, 256, 0, stream>>>(
        CTX, wot, bo, out, M, D_, NQ_);
}

// Round 21
// 87.788 us; speedup vs baseline: 1.0624x; 1.0624x over previous
//
#include <hip/hip_runtime.h>
#include <hip/hip_bf16.h>

#define B_  2
#define T_  2048
#define D_  512
#define DM_ 64
#define H_  16
#define NQ_ (DM_*H_)   // 1024
#define NT_ (T_/64)    // 32 key tiles

typedef __bf16 bf16x8 __attribute__((ext_vector_type(8)));
typedef __bf16 bf16x4 __attribute__((ext_vector_type(4)));
typedef float  f32x4  __attribute__((ext_vector_type(4)));
typedef unsigned int u32;

static __device__ __forceinline__ __bf16 bfc(float x) { return (__bf16)x; }
static __device__ __forceinline__ unsigned short f2bf(float x) {
    __bf16 b = (__bf16)x;
    unsigned short u;
    __builtin_memcpy(&u, &b, 2);
    return u;
}

#if __has_builtin(__builtin_amdgcn_exp2f)
static __device__ __forceinline__ float EXP2(float x) { return __builtin_amdgcn_exp2f(x); }
#else
static __device__ __forceinline__ float EXP2(float x) {
    float r; asm("v_exp_f32 %0, %1\ns_nop 0" : "=v"(r) : "v"(x)); return r;
}
#endif

// async global->LDS, 16B per lane; dest = wave-uniform base + lane*16
#define GLOAD16(gp, lp) \
    __builtin_amdgcn_global_load_lds((const __attribute__((address_space(1))) u32*)(gp), \
                                     (__attribute__((address_space(3))) u32*)(lp), 16, 0, 0)

// ---------------------------------------------------------------------------
// fused prep: [0,1024) pad | [1024,2048) data cvt | [2048,3584) qkv wtrans |
// [3584,4096) wo wtrans.  QKV wtrans writes permuted rows n' = h*64+dm.
// ---------------------------------------------------------------------------
__global__ __launch_bounds__(256)
void prep_kernel(const float* __restrict__ mask, float* __restrict__ padb,
                 const float* __restrict__ data, unsigned short* __restrict__ dataB,
                 const float* __restrict__ wq, const float* __restrict__ wk,
                 const float* __restrict__ wv, unsigned short* __restrict__ btall,
                 const float* __restrict__ wo, unsigned short* __restrict__ wot)
{
    __shared__ float t[32][33];
    const int bid = blockIdx.x;
    const int tid = threadIdx.x;
    if (bid < 1024) {
        const int row  = bid * 4 + (tid >> 6);
        const int lane = tid & 63;
        const float* p = mask + (size_t)row * D_;
        float4 a = *(const float4*)&p[lane * 8];
        float4 b = *(const float4*)&p[lane * 8 + 4];
        float s = a.x + a.y + a.z + a.w + b.x + b.y + b.z + b.w;
#pragma unroll
        for (int off = 32; off; off >>= 1) s += __shfl_down(s, off);
        if (lane == 0) padb[row] = (s == 0.0f) ? -1e9f : 0.0f;
    } else if (bid < 2048) {
        int i = ((bid - 1024) * 256 + tid) * 8;
        float4 a = *(const float4*)&data[i];
        float4 b = *(const float4*)&data[i + 4];
        bf16x8 u = {bfc(a.x), bfc(a.y), bfc(a.z), bfc(a.w),
                    bfc(b.x), bfc(b.y), bfc(b.z), bfc(b.w)};
        *(bf16x8*)&dataB[i] = u;
    } else if (bid < 3584) {
        const int idx = bid - 2048;
        const int z = idx >> 9, rem = idx & 511;
        const int c0 = (rem & 31) * 32, r0 = (rem >> 5) * 32;   // C=1024, R=512
        const float* in = (z == 0) ? wq : (z == 1) ? wk : wv;
        unsigned short* out = btall + (size_t)z * NQ_ * D_;
        const int tx = tid & 31, ty = tid >> 5;
#pragma unroll
        for (int i = 0; i < 4; ++i)
            t[ty * 4 + i][tx] = in[(size_t)(r0 + ty * 4 + i) * NQ_ + c0 + tx];
        __syncthreads();
#pragma unroll
        for (int i = 0; i < 4; ++i) {
            int c  = c0 + ty * 4 + i;
            int rp = (c & 15) * 64 + (c >> 4);   // n' = h*64 + dm
            out[(size_t)rp * D_ + r0 + tx] = f2bf(t[tx][ty * 4 + i]);
        }
    } else {
        const int idx = bid - 3584;
        const int c0 = (idx & 15) * 32, r0 = (idx >> 4) * 32;   // C=512, R=1024
        const int tx = tid & 31, ty = tid >> 5;
#pragma unroll
        for (int i = 0; i < 4; ++i)
            t[ty * 4 + i][tx] = wo[(size_t)(r0 + ty * 4 + i) * D_ + c0 + tx];
        __syncthreads();
#pragma unroll
        for (int i = 0; i < 4; ++i)
            wot[(size_t)(c0 + ty * 4 + i) * NQ_ + r0 + tx] = f2bf(t[tx][ty * 4 + i]);
    }
}

// ---------------------------------------------------------------------------
// fused QKV GEMM, 64x128 tile, XCD-chunked 1-D grid (1536 blocks).
// ---------------------------------------------------------------------------
__global__ __launch_bounds__(256)
void mgemm_qkv_kernel(const unsigned short* __restrict__ A,
                      const unsigned short* __restrict__ BtAll,
                      const float* __restrict__ bq, const float* __restrict__ bk,
                      const float* __restrict__ bv,
                      unsigned short* __restrict__ Qh, unsigned short* __restrict__ Kh,
                      unsigned short* __restrict__ Vt, float alpha_q)
{
    const int K = D_;
    __shared__ __align__(16) unsigned short Al[2][64 * 64];    // 16KB
    __shared__ __align__(16) unsigned short Bl[2][128 * 64];   // 32KB

    const int tid = threadIdx.x;
    const int w  = tid >> 6, l = tid & 63;
    const int lo = l & 15,  g = l >> 4;
    const int wri = w >> 1, wci = w & 1;

    const int f  = blockIdx.x;
    const int s  = f >> 3;
    const int mt = (f & 7) * 8 + (s / 24);
    const int nt = s % 24;
    const int m0 = mt * 64, n0 = nt * 128;

    const int lrow = l >> 3;
    const int lslot = (l & 7) ^ lrow;

    f32x4 acc[2][4] = {};
    const int nk = K >> 6;   // 8

#pragma unroll
    for (int p = 0; p < 2; ++p) {
        int br = w * 16 + p * 8;
        GLOAD16(A + (size_t)(m0 + br + lrow) * K + lslot * 8, (char*)Al[0] + br * 128);
    }
#pragma unroll
    for (int p = 0; p < 4; ++p) {
        int br = w * 32 + p * 8;
        GLOAD16(BtAll + (size_t)(n0 + br + lrow) * K + lslot * 8, (char*)Bl[0] + br * 128);
    }
    __syncthreads();

    for (int t = 0; t < nk; ++t) {
        const int cur = t & 1;
        if (t + 1 < nk) {
            const int k0 = (t + 1) << 6;
#pragma unroll
            for (int p = 0; p < 2; ++p) {
                int br = w * 16 + p * 8;
                GLOAD16(A + (size_t)(m0 + br + lrow) * K + k0 + lslot * 8,
                        (char*)Al[cur ^ 1] + br * 128);
            }
#pragma unroll
            for (int p = 0; p < 4; ++p) {
                int br = w * 32 + p * 8;
                GLOAD16(BtAll + (size_t)(n0 + br + lrow) * K + k0 + lslot * 8,
                        (char*)Bl[cur ^ 1] + br * 128);
            }
        }
#pragma unroll
        for (int kk = 0; kk < 2; ++kk) {
            bf16x8 af[2], bfr[4];
#pragma unroll
            for (int i = 0; i < 2; ++i) {
                int row = wri * 32 + i * 16 + lo;
                af[i] = *(const bf16x8*)&Al[cur][row * 64 + ((((kk << 2) + g) ^ (row & 7)) << 3)];
            }
#pragma unroll
            for (int j = 0; j < 4; ++j) {
                int col = wci * 64 + j * 16 + lo;
                bfr[j] = *(const bf16x8*)&Bl[cur][col * 64 + ((((kk << 2) + g) ^ (col & 7)) << 3)];
            }
#pragma unroll
            for (int i = 0; i < 2; ++i)
#pragma unroll
                for (int j = 0; j < 4; ++j)
                    acc[i][j] = __builtin_amdgcn_mfma_f32_16x16x32_bf16(af[i], bfr[j], acc[i][j], 0, 0, 0);
        }
        __syncthreads();
    }

    const int seg = n0 >> 10;
    const int n0l = n0 & 1023;
    const float* bias = (seg == 0) ? bq : (seg == 1) ? bk : bv;
    const float alpha = (seg == 0) ? alpha_q : 1.0f;
    const int h = (n0l >> 6) + wci;

    float bb[4];
#pragma unroll
    for (int j = 0; j < 4; ++j) bb[j] = bias[(j * 16 + lo) * 16 + h];

    if (seg < 2) {
        unsigned short* o16 = (seg == 0) ? Qh : Kh;
        unsigned short* hb = (unsigned short*)Al + wci * (64 * 64);
#pragma unroll
        for (int i = 0; i < 2; ++i)
#pragma unroll
            for (int jj = 0; jj < 4; ++jj) {
                int ml = wri * 32 + i * 16 + g * 4 + jj;
#pragma unroll
                for (int j = 0; j < 4; ++j) {
                    int dm = j * 16 + lo;
                    int off = ml * 64 + (((dm >> 3) ^ (ml & 7)) << 3) + (dm & 7);
                    hb[off] = f2bf((acc[i][j][jj] + bb[j]) * alpha);
                }
            }
        const int rrow = l >> 3, rch = l & 7;
#pragma unroll
        for (int p = 0; p < 4; ++p) {
            int ml = wri * 32 + p * 8 + rrow;
            bf16x8 v = *(const bf16x8*)&hb[ml * 64 + ((rch ^ (ml & 7)) << 3)];
            int m = m0 + ml;
            int t = m & (T_ - 1), bidx = m >> 11;
            *(bf16x8*)&o16[(((size_t)(bidx * H_ + h)) * T_ + t) * DM_ + rch * 8] = v;
        }
    } else {
#pragma unroll
        for (int i = 0; i < 2; ++i)
#pragma unroll
            for (int j = 0; j < 4; ++j) {
                int m = m0 + wri * 32 + i * 16 + g * 4;
                int t = m & (T_ - 1), bidx = m >> 11;
                int dm = j * 16 + lo;
                bf16x4 u = {bfc(acc[i][j][0] + bb[j]), bfc(acc[i][j][1] + bb[j]),
                            bfc(acc[i][j][2] + bb[j]), bfc(acc[i][j][3] + bb[j])};
                *(bf16x4*)&Vt[((size_t)(bidx * H_ + h) * DM_ + dm) * T_ + t] = u;
            }
    }
}

// ---------------------------------------------------------------------------
// out-projection GEMM (fp32 out), 64x64 tile, XCD-chunked 1-D grid (512).
// ---------------------------------------------------------------------------
__global__ __launch_bounds__(256)
void mgemm_out_kernel(const unsigned short* __restrict__ A,
                      const unsigned short* __restrict__ Bt,
                      const float* __restrict__ bias, float* __restrict__ out,
                      int M, int N, int K)
{
    __shared__ __align__(16) unsigned short Al[2][64 * 64];
    __shared__ __align__(16) unsigned short Bl[2][64 * 64];

    const int tid = threadIdx.x;
    const int w  = tid >> 6, l = tid & 63;
    const int lo = l & 15,  g = l >> 4;
    const int wri = w >> 1, wci = w & 1;

    const int f  = blockIdx.x;
    const int s  = f >> 3;
    const int mt = (f & 7) * 8 + (s >> 3);
    const int nt = s & 7;
    const int m0 = mt * 64, n0 = nt * 64;

    const int lrow = l >> 3;
    const int lslot = (l & 7) ^ lrow;

    f32x4 acc[2][2] = {};
    const int nk = K >> 6;   // 16

#pragma unroll
    for (int p = 0; p < 2; ++p) {
        int br = w * 16 + p * 8;
        GLOAD16(A  + (size_t)(m0 + br + lrow) * K + lslot * 8, (char*)Al[0] + br * 128);
        GLOAD16(Bt + (size_t)(n0 + br + lrow) * K + lslot * 8, (char*)Bl[0] + br * 128);
    }
    __syncthreads();

    for (int t = 0; t < nk; ++t) {
        const int cur = t & 1;
        if (t + 1 < nk) {
            const int k0 = (t + 1) << 6;
#pragma unroll
            for (int p = 0; p < 2; ++p) {
                int br = w * 16 + p * 8;
                GLOAD16(A  + (size_t)(m0 + br + lrow) * K + k0 + lslot * 8,
                        (char*)Al[cur ^ 1] + br * 128);
                GLOAD16(Bt + (size_t)(n0 + br + lrow) * K + k0 + lslot * 8,
                        (char*)Bl[cur ^ 1] + br * 128);
            }
        }
#pragma unroll
        for (int kk = 0; kk < 2; ++kk) {
            bf16x8 af[2], bfr[2];
#pragma unroll
            for (int i = 0; i < 2; ++i) {
                int row = wri * 32 + i * 16 + lo;
                af[i] = *(const bf16x8*)&Al[cur][row * 64 + ((((kk << 2) + g) ^ (row & 7)) << 3)];
                int col = wci * 32 + i * 16 + lo;
                bfr[i] = *(const bf16x8*)&Bl[cur][col * 64 + ((((kk << 2) + g) ^ (col & 7)) << 3)];
            }
#pragma unroll
            for (int i = 0; i < 2; ++i)
#pragma unroll
                for (int j = 0; j < 2; ++j)
                    acc[i][j] = __builtin_amdgcn_mfma_f32_16x16x32_bf16(af[i], bfr[j], acc[i][j], 0, 0, 0);
        }
        __syncthreads();
    }

    const int mb = m0 + wri * 32 + g * 4;
#pragma unroll
    for (int j = 0; j < 2; ++j) {
        int n = n0 + wci * 32 + j * 16 + lo;
        float bb = bias[n];
#pragma unroll
        for (int i = 0; i < 2; ++i)
#pragma unroll
            for (int jj = 0; jj < 4; ++jj) {
                int m = mb + i * 16 + jj;
                out[(size_t)m * N + n] = acc[i][j][jj] + bb;
            }
    }
}

// ---------------------------------------------------------------------------
// MFMA flash attention v21 = v18 + lean softmax:
//  - exp2 in place; pf built by DIRECT bf16x8 vector init (compiler emits
//    cvt_pk; no manual bit packing);
//  - l-sum via ones-MFMA: mfma(ones, pf, lacc) gives Sum_k P[k][q] in every
//    row -> deletes 32 VALU adds/tile AND both epilogue shfl reductions;
//    l now sums the same bf16-rounded P the numerator uses (consistent).
// Triple-buffered K/V, counted vmcnt, raw s_barrier, XCD-aware grid.
// ---------------------------------------------------------------------------
__global__ __launch_bounds__(256, 2)
void attn_kernel(const unsigned short* __restrict__ Qh,
                 const unsigned short* __restrict__ Kh,
                 const unsigned short* __restrict__ Vt,
                 const float* __restrict__ padb,
                 unsigned short* __restrict__ ctx)
{
    __shared__ __align__(16) unsigned short Ks[3][64 * 64];   // 24KB
    __shared__ __align__(16) unsigned short Vs[3][64 * 64];   // 24KB
    __shared__ __align__(16) float pbs[T_];                   // 8KB

    const int tid  = threadIdx.x;
    const int w    = tid >> 6;
    const int l    = tid & 63;
    const int lo16 = l & 15;
    const int g    = l >> 4;
    const int lrow = l >> 3;
    const int lslot = (l & 7) ^ lrow;

    const int f   = blockIdx.x;
    const int s   = f >> 3;
    const int bh  = (f & 7) * 4 + (s >> 4);
    const int q0  = (s & 15) * 128;
    const int bb  = bh >> 4;
    const int hh  = bh & 15;

    bf16x8 qf[2][2];
#pragma unroll
    for (int qt = 0; qt < 2; ++qt) {
        const unsigned short* Qp =
            Qh + ((size_t)bh * T_ + q0 + w * 32 + qt * 16 + lo16) * DM_ + g * 8;
        qf[qt][0] = *(const bf16x8*)(Qp);
        qf[qt][1] = *(const bf16x8*)(Qp + 32);
    }

    // all-ones A-frag for the l-sum MFMA
    bf16x8 ones;
#pragma unroll
    for (int i = 0; i < 8; ++i) ones[i] = (__bf16)1.0f;

    const unsigned short* kgp =
        Kh + (size_t)bh * T_ * DM_ + (size_t)(w * 16 + lrow) * DM_ + lslot * 8;
    const unsigned short* vgp =
        Vt + (size_t)bh * DM_ * T_ + (size_t)(w * 16 + lrow) * T_ + lslot * 8;

    {
        const float* src = padb + bb * T_ + tid * 8;
        float4 a = *(const float4*)(src);
        float4 b = *(const float4*)(src + 4);
        *(float4*)&pbs[tid * 8]     = a;
        *(float4*)&pbs[tid * 8 + 4] = b;
    }

    GLOAD16(kgp,           (char*)Ks[0] + (w * 16) * 128);
    GLOAD16(kgp + 8 * DM_, (char*)Ks[0] + (w * 16 + 8) * 128);
    GLOAD16(vgp,           (char*)Vs[0] + (w * 16) * 128);
    GLOAD16(vgp + 8 * T_,  (char*)Vs[0] + (w * 16 + 8) * 128);
    kgp += 64 * DM_; vgp += 64;
    GLOAD16(kgp,           (char*)Ks[1] + (w * 16) * 128);
    GLOAD16(kgp + 8 * DM_, (char*)Ks[1] + (w * 16 + 8) * 128);
    GLOAD16(vgp,           (char*)Vs[1] + (w * 16) * 128);
    GLOAD16(vgp + 8 * T_,  (char*)Vs[1] + (w * 16 + 8) * 128);
    kgp += 64 * DM_; vgp += 64;

    asm volatile("s_waitcnt vmcnt(4)" ::: "memory");
    __builtin_amdgcn_sched_barrier(0);
    __builtin_amdgcn_s_barrier();

    f32x4 oa[2][4] = {};
    f32x4 lacc[2] = {};

    char* Kr = (char*)Ks[0]; char* Kn = (char*)Ks[1]; char* Kw = (char*)Ks[2];
    char* Vr = (char*)Vs[0]; char* Vn = (char*)Vs[1]; char* Vw = (char*)Vs[2];

    for (int t = 0; t < NT_; ++t) {
        const bool more2 = (t + 2 < NT_);
        if (more2) {
            GLOAD16(kgp,           Kw + (w * 16) * 128);
            GLOAD16(kgp + 8 * DM_, Kw + (w * 16 + 8) * 128);
            GLOAD16(vgp,           Vw + (w * 16) * 128);
            GLOAD16(vgp + 8 * T_,  Vw + (w * 16 + 8) * 128);
            kgp += 64 * DM_;
            vgp += 64;
        }

        // ---- QK: C-init = pad bias (key-indexed) from LDS
        f32x4 sa[2][4];
#pragma unroll
        for (int nt = 0; nt < 4; ++nt) {
            f32x4 pb4 = *(const f32x4*)&pbs[t * 64 + nt * 16 + g * 4];
            sa[0][nt] = pb4;
            sa[1][nt] = pb4;
        }
        __builtin_amdgcn_s_setprio(1);
#pragma unroll
        for (int ks = 0; ks < 2; ++ks) {
#pragma unroll
            for (int nt = 0; nt < 4; ++nt) {
                int row = nt * 16 + lo16;
                int off = (row * 128 + ks * 64 + g * 16) ^ ((row & 7) << 4);
                bf16x8 kf = *(const bf16x8*)(Kr + off);
#pragma unroll
                for (int qt = 0; qt < 2; ++qt)
                    sa[qt][nt] = __builtin_amdgcn_mfma_f32_16x16x32_bf16(kf, qf[qt][ks], sa[qt][nt], 0, 0, 0);
            }
        }
        __builtin_amdgcn_s_setprio(0);

        // ---- softmax: exp2 in place; pf by direct vector init (cvt_pk)
#pragma unroll
        for (int qt = 0; qt < 2; ++qt)
#pragma unroll
            for (int nt = 0; nt < 4; ++nt) {
                sa[qt][nt][0] = EXP2(sa[qt][nt][0]);
                sa[qt][nt][1] = EXP2(sa[qt][nt][1]);
                sa[qt][nt][2] = EXP2(sa[qt][nt][2]);
                sa[qt][nt][3] = EXP2(sa[qt][nt][3]);
            }
        bf16x8 pf[2][2];
#pragma unroll
        for (int qt = 0; qt < 2; ++qt)
#pragma unroll
            for (int ks = 0; ks < 2; ++ks)
                pf[qt][ks] = (bf16x8){
                    bfc(sa[qt][2 * ks][0]), bfc(sa[qt][2 * ks][1]),
                    bfc(sa[qt][2 * ks][2]), bfc(sa[qt][2 * ks][3]),
                    bfc(sa[qt][2 * ks + 1][0]), bfc(sa[qt][2 * ks + 1][1]),
                    bfc(sa[qt][2 * ks + 1][2]), bfc(sa[qt][2 * ks + 1][3])};

        // ---- PV + l-sum MFMAs (lane-local key order; V b64-chunk reads)
        __builtin_amdgcn_s_setprio(1);
#pragma unroll
        for (int ks = 0; ks < 2; ++ks) {
#pragma unroll
            for (int qt = 0; qt < 2; ++qt)
                lacc[qt] = __builtin_amdgcn_mfma_f32_16x16x32_bf16(ones, pf[qt][ks], lacc[qt], 0, 0, 0);
#pragma unroll
            for (int nd = 0; nd < 4; ++nd) {
                int row = nd * 16 + lo16;
                int sw = (row & 7) << 4;
                int o0 = (row * 128 + ks * 64 + g * 8) ^ sw;
                int o1 = (row * 128 + ks * 64 + 32 + g * 8) ^ sw;
                uint2 a = *(const uint2*)(Vr + o0);
                uint2 b = *(const uint2*)(Vr + o1);
                uint4 uu; uu.x = a.x; uu.y = a.y; uu.z = b.x; uu.w = b.y;
                bf16x8 vf = *(const bf16x8*)&uu;
#pragma unroll
                for (int qt = 0; qt < 2; ++qt)
                    oa[qt][nd] = __builtin_amdgcn_mfma_f32_16x16x32_bf16(vf, pf[qt][ks], oa[qt][nd], 0, 0, 0);
            }
        }
        __builtin_amdgcn_s_setprio(0);

        if (t + 1 < NT_) {
            if (more2) {
                asm volatile("s_waitcnt vmcnt(4)" ::: "memory");
            } else {
                asm volatile("s_waitcnt vmcnt(0)" ::: "memory");
            }
            __builtin_amdgcn_sched_barrier(0);
            __builtin_amdgcn_s_barrier();
        }

        { char* tk = Kr; Kr = Kn; Kn = Kw; Kw = tk;
          char* tv = Vr; Vr = Vn; Vn = Vw; Vw = tv; }
    }

    // ---- epilogue: l fully reduced by the ones-MFMA (every row = sum)
#pragma unroll
    for (int qt = 0; qt < 2; ++qt) {
        float linv = 1.0f / lacc[qt][0];
        const size_t crow =
            ((size_t)(bb * T_ + q0 + w * 32 + qt * 16 + lo16)) * NQ_ + hh * DM_;
#pragma unroll
        for (int nd = 0; nd < 4; ++nd) {
            bf16x4 u = {bfc(oa[qt][nd][0] * linv), bfc(oa[qt][nd][1] * linv),
                        bfc(oa[qt][nd][2] * linv), bfc(oa[qt][nd][3] * linv)};
            *(bf16x4*)&ctx[crow + nd * 16 + g * 4] = u;
        }
    }
}

// ---------------------------------------------------------------------------
extern "C" void kernel_launch(void* const* d_in, const int* in_sizes, int n_in,
                              void* d_out, int out_size, void* d_ws, size_t ws_size,
                              hipStream_t stream) {
    const float* data = (const float*)d_in[0];
    const float* mask = (const float*)d_in[1];
    const float* wq   = (const float*)d_in[2];
    const float* bq   = (const float*)d_in[3];
    const float* wk   = (const float*)d_in[4];
    const float* bk   = (const float*)d_in[5];
    const float* wv   = (const float*)d_in[6];
    const float* bv   = (const float*)d_in[7];
    const float* wo   = (const float*)d_in[8];
    const float* bo   = (const float*)d_in[9];
    float* out = (float*)d_out;

    char* ws = (char*)d_ws;
    const size_t MB = 1024 * 1024;
    unsigned short* Qh    = (unsigned short*)(ws);             // 8MB
    unsigned short* Kh    = (unsigned short*)(ws +  8 * MB);   // 8MB
    unsigned short* Vt    = (unsigned short*)(ws + 16 * MB);   // 8MB
    unsigned short* CTX   = (unsigned short*)(ws + 24 * MB);   // 8MB (bf16)
    unsigned short* dataB = (unsigned short*)(ws + 32 * MB);   // 4MB
    unsigned short* BtAll = (unsigned short*)(ws + 36 * MB);   // 3MB
    unsigned short* wot   = (unsigned short*)(ws + 39 * MB);   // 1MB
    float*          padb  = (float*)         (ws + 40 * MB);   // 16KB

    const int M = B_ * T_;                 // 4096
    const float alpha_q = 0.125f * 1.44269504089f;

    prep_kernel<<<4096, 256, 0, stream>>>(mask, padb, data, dataB,
                                          wq, wk, wv, BtAll, wo, wot);

    mgemm_qkv_kernel<<<1536, 256, 0, stream>>>(
        dataB, BtAll, bq, bk, bv, Qh, Kh, Vt, alpha_q);

    attn_kernel<<<512, 256, 0, stream>>>(Qh, Kh, Vt, padb, CTX);

    mgemm_out_kernel<<<512, 256, 0, stream>>>(
        CTX, wot, bo, out, M, D_, NQ_);
}

// Round 22
// 87.741 us; speedup vs baseline: 1.0630x; 1.0005x over previous
//
#include <hip/hip_runtime.h>
#include <hip/hip_bf16.h>

#define B_  2
#define T_  2048
#define D_  512
#define DM_ 64
#define H_  16
#define NQ_ (DM_*H_)   // 1024
#define NT_ (T_/64)    // 32 key tiles

typedef __bf16 bf16x8 __attribute__((ext_vector_type(8)));
typedef __bf16 bf16x4 __attribute__((ext_vector_type(4)));
typedef float  f32x4  __attribute__((ext_vector_type(4)));
typedef unsigned int u32;

static __device__ __forceinline__ __bf16 bfc(float x) { return (__bf16)x; }
static __device__ __forceinline__ unsigned short f2bf(float x) {
    __bf16 b = (__bf16)x;
    unsigned short u;
    __builtin_memcpy(&u, &b, 2);
    return u;
}

#if __has_builtin(__builtin_amdgcn_exp2f)
static __device__ __forceinline__ float EXP2(float x) { return __builtin_amdgcn_exp2f(x); }
#else
static __device__ __forceinline__ float EXP2(float x) {
    float r; asm("v_exp_f32 %0, %1\ns_nop 0" : "=v"(r) : "v"(x)); return r;
}
#endif

// async global->LDS, 16B per lane; dest = wave-uniform base + lane*16
#define GLOAD16(gp, lp) \
    __builtin_amdgcn_global_load_lds((const __attribute__((address_space(1))) u32*)(gp), \
                                     (__attribute__((address_space(3))) u32*)(lp), 16, 0, 0)

// ---------------------------------------------------------------------------
// fused prep: [0,1024) pad | [1024,2048) data cvt | [2048,3584) qkv wtrans |
// [3584,4096) wo wtrans.  QKV wtrans writes permuted rows n' = h*64+dm.
// ---------------------------------------------------------------------------
__global__ __launch_bounds__(256)
void prep_kernel(const float* __restrict__ mask, float* __restrict__ padb,
                 const float* __restrict__ data, unsigned short* __restrict__ dataB,
                 const float* __restrict__ wq, const float* __restrict__ wk,
                 const float* __restrict__ wv, unsigned short* __restrict__ btall,
                 const float* __restrict__ wo, unsigned short* __restrict__ wot)
{
    __shared__ float t[32][33];
    const int bid = blockIdx.x;
    const int tid = threadIdx.x;
    if (bid < 1024) {
        const int row  = bid * 4 + (tid >> 6);
        const int lane = tid & 63;
        const float* p = mask + (size_t)row * D_;
        float4 a = *(const float4*)&p[lane * 8];
        float4 b = *(const float4*)&p[lane * 8 + 4];
        float s = a.x + a.y + a.z + a.w + b.x + b.y + b.z + b.w;
#pragma unroll
        for (int off = 32; off; off >>= 1) s += __shfl_down(s, off);
        if (lane == 0) padb[row] = (s == 0.0f) ? -1e9f : 0.0f;
    } else if (bid < 2048) {
        int i = ((bid - 1024) * 256 + tid) * 8;
        float4 a = *(const float4*)&data[i];
        float4 b = *(const float4*)&data[i + 4];
        bf16x8 u = {bfc(a.x), bfc(a.y), bfc(a.z), bfc(a.w),
                    bfc(b.x), bfc(b.y), bfc(b.z), bfc(b.w)};
        *(bf16x8*)&dataB[i] = u;
    } else if (bid < 3584) {
        const int idx = bid - 2048;
        const int z = idx >> 9, rem = idx & 511;
        const int c0 = (rem & 31) * 32, r0 = (rem >> 5) * 32;   // C=1024, R=512
        const float* in = (z == 0) ? wq : (z == 1) ? wk : wv;
        unsigned short* out = btall + (size_t)z * NQ_ * D_;
        const int tx = tid & 31, ty = tid >> 5;
#pragma unroll
        for (int i = 0; i < 4; ++i)
            t[ty * 4 + i][tx] = in[(size_t)(r0 + ty * 4 + i) * NQ_ + c0 + tx];
        __syncthreads();
#pragma unroll
        for (int i = 0; i < 4; ++i) {
            int c  = c0 + ty * 4 + i;
            int rp = (c & 15) * 64 + (c >> 4);   // n' = h*64 + dm
            out[(size_t)rp * D_ + r0 + tx] = f2bf(t[tx][ty * 4 + i]);
        }
    } else {
        const int idx = bid - 3584;
        const int c0 = (idx & 15) * 32, r0 = (idx >> 4) * 32;   // C=512, R=1024
        const int tx = tid & 31, ty = tid >> 5;
#pragma unroll
        for (int i = 0; i < 4; ++i)
            t[ty * 4 + i][tx] = wo[(size_t)(r0 + ty * 4 + i) * D_ + c0 + tx];
        __syncthreads();
#pragma unroll
        for (int i = 0; i < 4; ++i)
            wot[(size_t)(c0 + ty * 4 + i) * NQ_ + r0 + tx] = f2bf(t[tx][ty * 4 + i]);
    }
}

// ---------------------------------------------------------------------------
// fused QKV GEMM, 64x128 tile, XCD-chunked 1-D grid (1536 blocks).
// ---------------------------------------------------------------------------
__global__ __launch_bounds__(256)
void mgemm_qkv_kernel(const unsigned short* __restrict__ A,
                      const unsigned short* __restrict__ BtAll,
                      const float* __restrict__ bq, const float* __restrict__ bk,
                      const float* __restrict__ bv,
                      unsigned short* __restrict__ Qh, unsigned short* __restrict__ Kh,
                      unsigned short* __restrict__ Vt, float alpha_q)
{
    const int K = D_;
    __shared__ __align__(16) unsigned short Al[2][64 * 64];    // 16KB
    __shared__ __align__(16) unsigned short Bl[2][128 * 64];   // 32KB

    const int tid = threadIdx.x;
    const int w  = tid >> 6, l = tid & 63;
    const int lo = l & 15,  g = l >> 4;
    const int wri = w >> 1, wci = w & 1;

    const int f  = blockIdx.x;
    const int s  = f >> 3;
    const int mt = (f & 7) * 8 + (s / 24);
    const int nt = s % 24;
    const int m0 = mt * 64, n0 = nt * 128;

    const int lrow = l >> 3;
    const int lslot = (l & 7) ^ lrow;

    f32x4 acc[2][4] = {};
    const int nk = K >> 6;   // 8

#pragma unroll
    for (int p = 0; p < 2; ++p) {
        int br = w * 16 + p * 8;
        GLOAD16(A + (size_t)(m0 + br + lrow) * K + lslot * 8, (char*)Al[0] + br * 128);
    }
#pragma unroll
    for (int p = 0; p < 4; ++p) {
        int br = w * 32 + p * 8;
        GLOAD16(BtAll + (size_t)(n0 + br + lrow) * K + lslot * 8, (char*)Bl[0] + br * 128);
    }
    __syncthreads();

    for (int t = 0; t < nk; ++t) {
        const int cur = t & 1;
        if (t + 1 < nk) {
            const int k0 = (t + 1) << 6;
#pragma unroll
            for (int p = 0; p < 2; ++p) {
                int br = w * 16 + p * 8;
                GLOAD16(A + (size_t)(m0 + br + lrow) * K + k0 + lslot * 8,
                        (char*)Al[cur ^ 1] + br * 128);
            }
#pragma unroll
            for (int p = 0; p < 4; ++p) {
                int br = w * 32 + p * 8;
                GLOAD16(BtAll + (size_t)(n0 + br + lrow) * K + k0 + lslot * 8,
                        (char*)Bl[cur ^ 1] + br * 128);
            }
        }
#pragma unroll
        for (int kk = 0; kk < 2; ++kk) {
            bf16x8 af[2], bfr[4];
#pragma unroll
            for (int i = 0; i < 2; ++i) {
                int row = wri * 32 + i * 16 + lo;
                af[i] = *(const bf16x8*)&Al[cur][row * 64 + ((((kk << 2) + g) ^ (row & 7)) << 3)];
            }
#pragma unroll
            for (int j = 0; j < 4; ++j) {
                int col = wci * 64 + j * 16 + lo;
                bfr[j] = *(const bf16x8*)&Bl[cur][col * 64 + ((((kk << 2) + g) ^ (col & 7)) << 3)];
            }
#pragma unroll
            for (int i = 0; i < 2; ++i)
#pragma unroll
                for (int j = 0; j < 4; ++j)
                    acc[i][j] = __builtin_amdgcn_mfma_f32_16x16x32_bf16(af[i], bfr[j], acc[i][j], 0, 0, 0);
        }
        __syncthreads();
    }

    const int seg = n0 >> 10;
    const int n0l = n0 & 1023;
    const float* bias = (seg == 0) ? bq : (seg == 1) ? bk : bv;
    const float alpha = (seg == 0) ? alpha_q : 1.0f;
    const int h = (n0l >> 6) + wci;

    float bb[4];
#pragma unroll
    for (int j = 0; j < 4; ++j) bb[j] = bias[(j * 16 + lo) * 16 + h];

    if (seg < 2) {
        unsigned short* o16 = (seg == 0) ? Qh : Kh;
        unsigned short* hb = (unsigned short*)Al + wci * (64 * 64);
#pragma unroll
        for (int i = 0; i < 2; ++i)
#pragma unroll
            for (int jj = 0; jj < 4; ++jj) {
                int ml = wri * 32 + i * 16 + g * 4 + jj;
#pragma unroll
                for (int j = 0; j < 4; ++j) {
                    int dm = j * 16 + lo;
                    int off = ml * 64 + (((dm >> 3) ^ (ml & 7)) << 3) + (dm & 7);
                    hb[off] = f2bf((acc[i][j][jj] + bb[j]) * alpha);
                }
            }
        const int rrow = l >> 3, rch = l & 7;
#pragma unroll
        for (int p = 0; p < 4; ++p) {
            int ml = wri * 32 + p * 8 + rrow;
            bf16x8 v = *(const bf16x8*)&hb[ml * 64 + ((rch ^ (ml & 7)) << 3)];
            int m = m0 + ml;
            int t = m & (T_ - 1), bidx = m >> 11;
            *(bf16x8*)&o16[(((size_t)(bidx * H_ + h)) * T_ + t) * DM_ + rch * 8] = v;
        }
    } else {
#pragma unroll
        for (int i = 0; i < 2; ++i)
#pragma unroll
            for (int j = 0; j < 4; ++j) {
                int m = m0 + wri * 32 + i * 16 + g * 4;
                int t = m & (T_ - 1), bidx = m >> 11;
                int dm = j * 16 + lo;
                bf16x4 u = {bfc(acc[i][j][0] + bb[j]), bfc(acc[i][j][1] + bb[j]),
                            bfc(acc[i][j][2] + bb[j]), bfc(acc[i][j][3] + bb[j])};
                *(bf16x4*)&Vt[((size_t)(bidx * H_ + h) * DM_ + dm) * T_ + t] = u;
            }
    }
}

// ---------------------------------------------------------------------------
// out-projection GEMM (fp32 out), 64x64 tile, XCD-chunked 1-D grid (512).
// ---------------------------------------------------------------------------
__global__ __launch_bounds__(256)
void mgemm_out_kernel(const unsigned short* __restrict__ A,
                      const unsigned short* __restrict__ Bt,
                      const float* __restrict__ bias, float* __restrict__ out,
                      int M, int N, int K)
{
    __shared__ __align__(16) unsigned short Al[2][64 * 64];
    __shared__ __align__(16) unsigned short Bl[2][64 * 64];

    const int tid = threadIdx.x;
    const int w  = tid >> 6, l = tid & 63;
    const int lo = l & 15,  g = l >> 4;
    const int wri = w >> 1, wci = w & 1;

    const int f  = blockIdx.x;
    const int s  = f >> 3;
    const int mt = (f & 7) * 8 + (s >> 3);
    const int nt = s & 7;
    const int m0 = mt * 64, n0 = nt * 64;

    const int lrow = l >> 3;
    const int lslot = (l & 7) ^ lrow;

    f32x4 acc[2][2] = {};
    const int nk = K >> 6;   // 16

#pragma unroll
    for (int p = 0; p < 2; ++p) {
        int br = w * 16 + p * 8;
        GLOAD16(A  + (size_t)(m0 + br + lrow) * K + lslot * 8, (char*)Al[0] + br * 128);
        GLOAD16(Bt + (size_t)(n0 + br + lrow) * K + lslot * 8, (char*)Bl[0] + br * 128);
    }
    __syncthreads();

    for (int t = 0; t < nk; ++t) {
        const int cur = t & 1;
        if (t + 1 < nk) {
            const int k0 = (t + 1) << 6;
#pragma unroll
            for (int p = 0; p < 2; ++p) {
                int br = w * 16 + p * 8;
                GLOAD16(A  + (size_t)(m0 + br + lrow) * K + k0 + lslot * 8,
                        (char*)Al[cur ^ 1] + br * 128);
                GLOAD16(Bt + (size_t)(n0 + br + lrow) * K + k0 + lslot * 8,
                        (char*)Bl[cur ^ 1] + br * 128);
            }
        }
#pragma unroll
        for (int kk = 0; kk < 2; ++kk) {
            bf16x8 af[2], bfr[2];
#pragma unroll
            for (int i = 0; i < 2; ++i) {
                int row = wri * 32 + i * 16 + lo;
                af[i] = *(const bf16x8*)&Al[cur][row * 64 + ((((kk << 2) + g) ^ (row & 7)) << 3)];
                int col = wci * 32 + i * 16 + lo;
                bfr[i] = *(const bf16x8*)&Bl[cur][col * 64 + ((((kk << 2) + g) ^ (col & 7)) << 3)];
            }
#pragma unroll
            for (int i = 0; i < 2; ++i)
#pragma unroll
                for (int j = 0; j < 2; ++j)
                    acc[i][j] = __builtin_amdgcn_mfma_f32_16x16x32_bf16(af[i], bfr[j], acc[i][j], 0, 0, 0);
        }
        __syncthreads();
    }

    const int mb = m0 + wri * 32 + g * 4;
#pragma unroll
    for (int j = 0; j < 2; ++j) {
        int n = n0 + wci * 32 + j * 16 + lo;
        float bb = bias[n];
#pragma unroll
        for (int i = 0; i < 2; ++i)
#pragma unroll
            for (int jj = 0; jj < 4; ++jj) {
                int m = mb + i * 16 + jj;
                out[(size_t)m * N + n] = acc[i][j][jj] + bb;
            }
    }
}

// ---------------------------------------------------------------------------
// MFMA flash attention v22 = v21 + data-dependent pad fast path:
// per key-tile "has-pad" bitmask computed in the prologue from registers
// (__ballot), held in an SGPR. Fast path (no padding in tile): ZERO C-init
// -- no pb LDS reads, no lgkm wait ahead of QK. Slow path (tile has
// padding): original pb4 C-init from pbs. Uniform scalar branch.
// Lean softmax (exp2 in place, direct bf16x8 init, ones-MFMA l-sum),
// triple-buffered K/V, counted vmcnt, raw s_barrier, XCD-aware grid.
// ---------------------------------------------------------------------------
__global__ __launch_bounds__(256, 2)
void attn_kernel(const unsigned short* __restrict__ Qh,
                 const unsigned short* __restrict__ Kh,
                 const unsigned short* __restrict__ Vt,
                 const float* __restrict__ padb,
                 unsigned short* __restrict__ ctx)
{
    __shared__ __align__(16) unsigned short Ks[3][64 * 64];   // 24KB
    __shared__ __align__(16) unsigned short Vs[3][64 * 64];   // 24KB
    __shared__ __align__(16) float pbs[T_];                   // 8KB
    __shared__ unsigned long long wflags[4];

    const int tid  = threadIdx.x;
    const int w    = tid >> 6;
    const int l    = tid & 63;
    const int lo16 = l & 15;
    const int g    = l >> 4;
    const int lrow = l >> 3;
    const int lslot = (l & 7) ^ lrow;

    const int f   = blockIdx.x;
    const int s   = f >> 3;
    const int bh  = (f & 7) * 4 + (s >> 4);
    const int q0  = (s & 15) * 128;
    const int bb  = bh >> 4;
    const int hh  = bh & 15;

    bf16x8 qf[2][2];
#pragma unroll
    for (int qt = 0; qt < 2; ++qt) {
        const unsigned short* Qp =
            Qh + ((size_t)bh * T_ + q0 + w * 32 + qt * 16 + lo16) * DM_ + g * 8;
        qf[qt][0] = *(const bf16x8*)(Qp);
        qf[qt][1] = *(const bf16x8*)(Qp + 32);
    }

    // all-ones A-frag for the l-sum MFMA
    bf16x8 ones;
#pragma unroll
    for (int i = 0; i < 8; ++i) ones[i] = (__bf16)1.0f;

    const unsigned short* kgp =
        Kh + (size_t)bh * T_ * DM_ + (size_t)(w * 16 + lrow) * DM_ + lslot * 8;
    const unsigned short* vgp =
        Vt + (size_t)bh * DM_ * T_ + (size_t)(w * 16 + lrow) * T_ + lslot * 8;

    // pad-bias -> LDS; per-thread "any nonzero" flag from REGISTERS;
    // per-wave ballot -> wflags (thread tid covers keys tid*8..+7 = tile tid/8)
    {
        const float* src = padb + bb * T_ + tid * 8;
        float4 a = *(const float4*)(src);
        float4 b = *(const float4*)(src + 4);
        *(float4*)&pbs[tid * 8]     = a;
        *(float4*)&pbs[tid * 8 + 4] = b;
        bool any = (a.x != 0.f) | (a.y != 0.f) | (a.z != 0.f) | (a.w != 0.f) |
                   (b.x != 0.f) | (b.y != 0.f) | (b.z != 0.f) | (b.w != 0.f);
        unsigned long long bal = __ballot(any);
        if (l == 0) wflags[w] = bal;
    }

    GLOAD16(kgp,           (char*)Ks[0] + (w * 16) * 128);
    GLOAD16(kgp + 8 * DM_, (char*)Ks[0] + (w * 16 + 8) * 128);
    GLOAD16(vgp,           (char*)Vs[0] + (w * 16) * 128);
    GLOAD16(vgp + 8 * T_,  (char*)Vs[0] + (w * 16 + 8) * 128);
    kgp += 64 * DM_; vgp += 64;
    GLOAD16(kgp,           (char*)Ks[1] + (w * 16) * 128);
    GLOAD16(kgp + 8 * DM_, (char*)Ks[1] + (w * 16 + 8) * 128);
    GLOAD16(vgp,           (char*)Vs[1] + (w * 16) * 128);
    GLOAD16(vgp + 8 * T_,  (char*)Vs[1] + (w * 16 + 8) * 128);
    kgp += 64 * DM_; vgp += 64;

    // wait: tile0 loads done (tile1 in flight) + ALL LDS writes drained
    asm volatile("s_waitcnt vmcnt(4) lgkmcnt(0)" ::: "memory");
    __builtin_amdgcn_sched_barrier(0);
    __builtin_amdgcn_s_barrier();

    // build per-tile has-pad mask (tile wv*8+j <- byte j of wflags[wv])
    u32 tf = 0;
#pragma unroll
    for (int wv = 0; wv < 4; ++wv) {
        unsigned long long m = wflags[wv];
#pragma unroll
        for (int j = 0; j < 8; ++j)
            if ((m >> (8 * j)) & 0xFFull) tf |= 1u << (wv * 8 + j);
    }
    const u32 sflags = (u32)__builtin_amdgcn_readfirstlane((int)tf);

    f32x4 oa[2][4] = {};
    f32x4 lacc[2] = {};

    char* Kr = (char*)Ks[0]; char* Kn = (char*)Ks[1]; char* Kw = (char*)Ks[2];
    char* Vr = (char*)Vs[0]; char* Vn = (char*)Vs[1]; char* Vw = (char*)Vs[2];

    for (int t = 0; t < NT_; ++t) {
        const bool more2 = (t + 2 < NT_);
        if (more2) {
            GLOAD16(kgp,           Kw + (w * 16) * 128);
            GLOAD16(kgp + 8 * DM_, Kw + (w * 16 + 8) * 128);
            GLOAD16(vgp,           Vw + (w * 16) * 128);
            GLOAD16(vgp + 8 * T_,  Vw + (w * 16 + 8) * 128);
            kgp += 64 * DM_;
            vgp += 64;
        }

        // ---- QK: C-init = 0 (fast path) or pad bias (tile has padding)
        f32x4 sa[2][4];
        if ((sflags >> t) & 1) {
#pragma unroll
            for (int nt = 0; nt < 4; ++nt) {
                f32x4 pb4 = *(const f32x4*)&pbs[t * 64 + nt * 16 + g * 4];
                sa[0][nt] = pb4;
                sa[1][nt] = pb4;
            }
        } else {
#pragma unroll
            for (int nt = 0; nt < 4; ++nt) {
                sa[0][nt] = (f32x4){0.f, 0.f, 0.f, 0.f};
                sa[1][nt] = (f32x4){0.f, 0.f, 0.f, 0.f};
            }
        }
        __builtin_amdgcn_s_setprio(1);
#pragma unroll
        for (int ks = 0; ks < 2; ++ks) {
#pragma unroll
            for (int nt = 0; nt < 4; ++nt) {
                int row = nt * 16 + lo16;
                int off = (row * 128 + ks * 64 + g * 16) ^ ((row & 7) << 4);
                bf16x8 kf = *(const bf16x8*)(Kr + off);
#pragma unroll
                for (int qt = 0; qt < 2; ++qt)
                    sa[qt][nt] = __builtin_amdgcn_mfma_f32_16x16x32_bf16(kf, qf[qt][ks], sa[qt][nt], 0, 0, 0);
            }
        }
        __builtin_amdgcn_s_setprio(0);

        // ---- softmax: exp2 in place; pf by direct vector init (cvt_pk)
#pragma unroll
        for (int qt = 0; qt < 2; ++qt)
#pragma unroll
            for (int nt = 0; nt < 4; ++nt) {
                sa[qt][nt][0] = EXP2(sa[qt][nt][0]);
                sa[qt][nt][1] = EXP2(sa[qt][nt][1]);
                sa[qt][nt][2] = EXP2(sa[qt][nt][2]);
                sa[qt][nt][3] = EXP2(sa[qt][nt][3]);
            }
        bf16x8 pf[2][2];
#pragma unroll
        for (int qt = 0; qt < 2; ++qt)
#pragma unroll
            for (int ks = 0; ks < 2; ++ks)
                pf[qt][ks] = (bf16x8){
                    bfc(sa[qt][2 * ks][0]), bfc(sa[qt][2 * ks][1]),
                    bfc(sa[qt][2 * ks][2]), bfc(sa[qt][2 * ks][3]),
                    bfc(sa[qt][2 * ks + 1][0]), bfc(sa[qt][2 * ks + 1][1]),
                    bfc(sa[qt][2 * ks + 1][2]), bfc(sa[qt][2 * ks + 1][3])};

        // ---- PV + l-sum MFMAs (lane-local key order; V b64-chunk reads)
        __builtin_amdgcn_s_setprio(1);
#pragma unroll
        for (int ks = 0; ks < 2; ++ks) {
#pragma unroll
            for (int qt = 0; qt < 2; ++qt)
                lacc[qt] = __builtin_amdgcn_mfma_f32_16x16x32_bf16(ones, pf[qt][ks], lacc[qt], 0, 0, 0);
#pragma unroll
            for (int nd = 0; nd < 4; ++nd) {
                int row = nd * 16 + lo16;
                int sw = (row & 7) << 4;
                int o0 = (row * 128 + ks * 64 + g * 8) ^ sw;
                int o1 = (row * 128 + ks * 64 + 32 + g * 8) ^ sw;
                uint2 a = *(const uint2*)(Vr + o0);
                uint2 b = *(const uint2*)(Vr + o1);
                uint4 uu; uu.x = a.x; uu.y = a.y; uu.z = b.x; uu.w = b.y;
                bf16x8 vf = *(const bf16x8*)&uu;
#pragma unroll
                for (int qt = 0; qt < 2; ++qt)
                    oa[qt][nd] = __builtin_amdgcn_mfma_f32_16x16x32_bf16(vf, pf[qt][ks], oa[qt][nd], 0, 0, 0);
            }
        }
        __builtin_amdgcn_s_setprio(0);

        if (t + 1 < NT_) {
            if (more2) {
                asm volatile("s_waitcnt vmcnt(4)" ::: "memory");
            } else {
                asm volatile("s_waitcnt vmcnt(0)" ::: "memory");
            }
            __builtin_amdgcn_sched_barrier(0);
            __builtin_amdgcn_s_barrier();
        }

        { char* tk = Kr; Kr = Kn; Kn = Kw; Kw = tk;
          char* tv = Vr; Vr = Vn; Vn = Vw; Vw = tv; }
    }

    // ---- epilogue: l fully reduced by the ones-MFMA (every row = sum)
#pragma unroll
    for (int qt = 0; qt < 2; ++qt) {
        float linv = 1.0f / lacc[qt][0];
        const size_t crow =
            ((size_t)(bb * T_ + q0 + w * 32 + qt * 16 + lo16)) * NQ_ + hh * DM_;
#pragma unroll
        for (int nd = 0; nd < 4; ++nd) {
            bf16x4 u = {bfc(oa[qt][nd][0] * linv), bfc(oa[qt][nd][1] * linv),
                        bfc(oa[qt][nd][2] * linv), bfc(oa[qt][nd][3] * linv)};
            *(bf16x4*)&ctx[crow + nd * 16 + g * 4] = u;
        }
    }
}

// ---------------------------------------------------------------------------
extern "C" void kernel_launch(void* const* d_in, const int* in_sizes, int n_in,
                              void* d_out, int out_size, void* d_ws, size_t ws_size,
                              hipStream_t stream) {
    const float* data = (const float*)d_in[0];
    const float* mask = (const float*)d_in[1];
    const float* wq   = (const float*)d_in[2];
    const float* bq   = (const float*)d_in[3];
    const float* wk   = (const float*)d_in[4];
    const float* bk   = (const float*)d_in[5];
    const float* wv   = (const float*)d_in[6];
    const float* bv   = (const float*)d_in[7];
    const float* wo   = (const float*)d_in[8];
    const float* bo   = (const float*)d_in[9];
    float* out = (float*)d_out;

    char* ws = (char*)d_ws;
    const size_t MB = 1024 * 1024;
    unsigned short* Qh    = (unsigned short*)(ws);             // 8MB
    unsigned short* Kh    = (unsigned short*)(ws +  8 * MB);   // 8MB
    unsigned short* Vt    = (unsigned short*)(ws + 16 * MB);   // 8MB
    unsigned short* CTX   = (unsigned short*)(ws + 24 * MB);   // 8MB (bf16)
    unsigned short* dataB = (unsigned short*)(ws + 32 * MB);   // 4MB
    unsigned short* BtAll = (unsigned short*)(ws + 36 * MB);   // 3MB
    unsigned short* wot   = (unsigned short*)(ws + 39 * MB);   // 1MB
    float*          padb  = (float*)         (ws + 40 * MB);   // 16KB

    const int M = B_ * T_;                 // 4096
    const float alpha_q = 0.125f * 1.44269504089f;

    prep_kernel<<<4096, 256, 0, stream>>>(mask, padb, data, dataB,
                                          wq, wk, wv, BtAll, wo, wot);

    mgemm_qkv_kernel<<<1536, 256, 0, stream>>>(
        dataB, BtAll, bq, bk, bv, Qh, Kh, Vt, alpha_q);

    attn_kernel<<<512, 256, 0, stream>>>(Qh, Kh, Vt, padb, CTX);

    mgemm_out_kernel<<<512, 256, 0, stream>>>(
        CTX, wot, bo, out, M, D_, NQ_);
}